// Round 6
// baseline (343.058 us; speedup 1.0000x reference)
//
#include <hip/hip_runtime.h>
#include <hip/hip_bf16.h>
#include <stdint.h>

#define BATCH  8192
#define DIN    2048
#define DOUT   2048
#define NB     256
#define KSEL   26      // ceil(0.1*256)
#define GDELTA 1e-4f   // top-k boundary refine threshold

typedef __attribute__((ext_vector_type(2))) float f32x2;
typedef __attribute__((ext_vector_type(4))) float f32x4;
typedef __attribute__((ext_vector_type(16))) float f32x16;
typedef __attribute__((ext_vector_type(8))) __bf16 bf16x8;
typedef __attribute__((ext_vector_type(8))) unsigned short u16x8;
typedef __attribute__((ext_vector_type(4))) unsigned short u16x4;

__device__ __forceinline__ float bf2f(unsigned short u){
  union { unsigned int i; float f; } v; v.i = ((unsigned int)u) << 16; return v.f;
}
__device__ __forceinline__ unsigned short f2bf(float f){
  union { float f; unsigned int i; } v; v.f = f;
  unsigned int x = v.i;
  return (unsigned short)((x + 0x7FFFu + ((x >> 16) & 1u)) >> 16);  // RNE
}
__device__ __forceinline__ unsigned short f2bf_c(float f){
  __bf16 b = (__bf16)f;
  union { __bf16 b; unsigned short u; } v; v.b = b; return v.u;
}

// ---------------- K0b: W -> W^T bf16 (wt[n][k] = W[k][n]) ----------------
__global__ __launch_bounds__(256) void conv_wt(const float* __restrict__ w, unsigned short* __restrict__ wt)
{
  __shared__ float tl[64][65];
  const int k0 = blockIdx.x * 64;
  const int n0 = blockIdx.y * 64;
  const int c  = threadIdx.x & 63;
  const int r4 = threadIdx.x >> 6;
  #pragma unroll
  for (int i = 0; i < 16; i++){
    const int r = r4 * 16 + i;
    tl[r][c] = w[(size_t)(k0 + r) * DOUT + n0 + c];
  }
  __syncthreads();
  #pragma unroll
  for (int i = 0; i < 16; i++){
    const int n = r4 * 16 + i;
    wt[(size_t)(n0 + n) * DIN + k0 + c] = f2bf(tl[c][n]);
  }
}

// ---------------- K0c: gw -> transposed hi/lo bf16 split --------------------
__global__ __launch_bounds__(256) void conv_gwt(const float* __restrict__ gw,
    unsigned short* __restrict__ ghiT, unsigned short* __restrict__ gloT)
{
  __shared__ float tl[64][65];
  const int k0 = blockIdx.x * 64;
  const int n0 = blockIdx.y * 64;
  const int c  = threadIdx.x & 63;
  const int r4 = threadIdx.x >> 6;
  #pragma unroll
  for (int i = 0; i < 16; i++){
    const int r = r4 * 16 + i;
    tl[r][c] = gw[(size_t)(k0 + r) * NB + n0 + c];
  }
  __syncthreads();
  #pragma unroll
  for (int i = 0; i < 16; i++){
    const int n = r4 * 16 + i;
    const float v = tl[c][n];
    const unsigned short h = f2bf_c(v);
    ghiT[(size_t)(n0 + n) * DIN + k0 + c] = h;
    gloT[(size_t)(n0 + n) * DIN + k0 + c] = f2bf_c(v - bf2f(h));
  }
}

// ---------------- K1: FLIPPED gate GEMM via bf16 MFMA -----------------------
// part^T = g^T (M=256 c) x x^T (N=8192 b), K=2048 split 4.
// A (g hi/lo): only LDS-staged operand, 64c x 32k dbuf tiles (stride-40 pad).
// B (x): per-lane 16B f32 loads straight from global (B-frag layout == row-
// major x), converted hi/lo bf16 in regs, software-pipelined 1 K-step ahead.
// 3 terms: g_hi*x_hi + g_lo*x_hi + g_hi*x_lo (x_lo*g_lo dropped, sigma~1.6e-5;
// boundary rows exactly recomputed by refine). Frag geometry identical to the
// R5-verified kernel. Block: 64c x 256b, 4 waves (wave 64c x 64b, m2 x n2 of
// 32x32x16). Grid (4, 32, 4) = 512 blocks, 2/CU.
__global__ __launch_bounds__(256) void gate_flip(
    const float* __restrict__ x,
    const unsigned short* __restrict__ ghiT,
    const unsigned short* __restrict__ gloT,
    float* __restrict__ part)
{
  __shared__ unsigned short Ah[2][64][40], Al[2][64][40];   // 20.5 KB total

  const int c0   = blockIdx.x * 64;    // c-tile (gate col block)
  const int b0   = blockIdx.y * 256;   // b-tile (batch block)
  const int ks   = blockIdx.z;         // K-split 0..3
  const int k0   = ks * 512;
  const int t    = threadIdx.x;
  const int lane = t & 63;
  const int wv   = t >> 6;             // wave: b-strip wv*64
  const int l31  = lane & 31;
  const int lk   = (lane >> 5) * 8;    // k sub-offset

  // A staging map: c = t>>2, k8 = (t&3)*8
  const int sc = t >> 2;
  const int sk = (t & 3) * 8;

  f32x16 acc[2][2];
  #pragma unroll
  for (int m = 0; m < 2; m++)
    #pragma unroll
    for (int n = 0; n < 2; n++) acc[m][n] = (f32x16)0.f;

  auto STAGE = [&](int bb, int kc){
    *(u16x8*)&Ah[bb][sc][sk] = *(const u16x8*)&ghiT[(size_t)(c0 + sc) * DIN + kc + sk];
    *(u16x8*)&Al[bb][sc][sk] = *(const u16x8*)&gloT[(size_t)(c0 + sc) * DIN + kc + sk];
  };

  auto LOADB = [&](f32x4 (&xr)[2][2][2], int kc){   // [n][kh][half]
    #pragma unroll
    for (int n = 0; n < 2; n++){
      const size_t rowb = (size_t)(b0 + wv * 64 + n * 32 + l31) * DIN;
      #pragma unroll
      for (int kh = 0; kh < 2; kh++){
        const float* xp = &x[rowb + kc + kh * 16 + lk];
        xr[n][kh][0] = *(const f32x4*)xp;
        xr[n][kh][1] = *(const f32x4*)(xp + 4);
      }
    }
  };

  auto COMP = [&](const f32x4 (&xr)[2][2][2], int bb){
    bf16x8 bhf[2][2], blf[2][2];
    #pragma unroll
    for (int n = 0; n < 2; n++)
      #pragma unroll
      for (int kh = 0; kh < 2; kh++){
        bf16x8 h, l;
        #pragma unroll
        for (int q = 0; q < 2; q++)
          #pragma unroll
          for (int j = 0; j < 4; j++){
            const float v = xr[n][kh][q][j];
            const __bf16 hb = (__bf16)v;
            h[q * 4 + j] = hb;
            l[q * 4 + j] = (__bf16)(v - (float)hb);
          }
        bhf[n][kh] = h; blf[n][kh] = l;
      }
    #pragma unroll
    for (int kh = 0; kh < 2; kh++){
      const int ko = kh * 16 + lk;
      #pragma unroll
      for (int m = 0; m < 2; m++){
        const bf16x8 ah = *(const bf16x8*)&Ah[bb][m * 32 + l31][ko];
        const bf16x8 al = *(const bf16x8*)&Al[bb][m * 32 + l31][ko];
        #pragma unroll
        for (int n = 0; n < 2; n++){
          acc[m][n] = __builtin_amdgcn_mfma_f32_32x32x16_bf16(ah, bhf[n][kh], acc[m][n], 0, 0, 0);
          acc[m][n] = __builtin_amdgcn_mfma_f32_32x32x16_bf16(al, bhf[n][kh], acc[m][n], 0, 0, 0);
          acc[m][n] = __builtin_amdgcn_mfma_f32_32x32x16_bf16(ah, blf[n][kh], acc[m][n], 0, 0, 0);
        }
      }
    }
  };

  f32x4 xrA[2][2][2], xrB[2][2][2];
  LOADB(xrA, k0);
  STAGE(0, k0);
  __syncthreads();
  #pragma unroll 1
  for (int it = 0; it < 8; it++){
    const int kc = k0 + it * 64;
    // step A (s=2it): stage/load s+1 (always exists), compute buf0
    LOADB(xrB, kc + 32);
    STAGE(1, kc + 32);
    COMP(xrA, 0);
    __syncthreads();
    // step B (s=2it+1): stage/load s+1 if it<7, compute buf1
    if (it < 7){
      LOADB(xrA, kc + 64);
      STAGE(0, kc + 64);
    }
    COMP(xrB, 1);
    __syncthreads();
  }

  // C/D 32x32: col(lane&31)=b, row(reg)= (r&3)+8*(r>>2)+4*(lane>>5) = c
  float* dst = part + (size_t)ks * BATCH * NB;
  #pragma unroll
  for (int m = 0; m < 2; m++)
    #pragma unroll
    for (int n = 0; n < 2; n++){
      const int brow = b0 + wv * 64 + n * 32 + l31;
      #pragma unroll
      for (int r = 0; r < 16; r++){
        const int ccol = c0 + m * 32 + (r & 3) + 8 * (r >> 2) + 4 * (lane >> 5);
        dst[(size_t)brow * NB + ccol] = acc[m][n][r];
      }
    }
}

// ---------------- K2: sum 4 partials, top-26 + renorm + boundary flag -------
__global__ __launch_bounds__(256) void topk(float* __restrict__ part,
    const float* __restrict__ gb, int* __restrict__ flags)
{
  const int lane = threadIdx.x & 63;
  const int row  = blockIdx.x * 4 + (threadIdx.x >> 6);
  f32x4* p0 = (f32x4*)&part[(size_t)row * NB];
  const f32x4* p1 = (const f32x4*)&part[(size_t)(BATCH + row) * NB];
  const f32x4* p2 = (const f32x4*)&part[(size_t)(2 * BATCH + row) * NB];
  const f32x4* p3 = (const f32x4*)&part[(size_t)(3 * BATCH + row) * NB];
  const f32x4* gbv = (const f32x4*)gb;
  f32x4 v = ((p0[lane] + p1[lane]) + p2[lane]) + p3[lane] + gbv[lane];

  const float NEG = -3.402823466e38f;
  float w0 = v[0], w1 = v[1], w2 = v[2], w3 = v[3];
  float thr = 0.f, nxt = 0.f;
  for (int it = 0; it < KSEL + 1; it++){
    float lm = fmaxf(fmaxf(w0, w1), fmaxf(w2, w3));
    float wm = lm;
    #pragma unroll
    for (int off = 32; off; off >>= 1) wm = fmaxf(wm, __shfl_xor(wm, off, 64));
    unsigned long long ball = __ballot(lm == wm);
    int first = __ffsll(ball) - 1;
    if (lane == first){
      if      (w0 == wm) w0 = NEG;
      else if (w1 == wm) w1 = NEG;
      else if (w2 == wm) w2 = NEG;
      else               w3 = NEG;
    }
    if (it < KSEL) thr = wm; else nxt = wm;
  }
  if (lane == 0) flags[row] = (thr - nxt < GDELTA) ? 1 : 0;

  float s = 0.f;
  #pragma unroll
  for (int j = 0; j < 4; j++) s += (v[j] >= thr) ? v[j] : 0.f;
  #pragma unroll
  for (int off = 32; off; off >>= 1) s += __shfl_xor(s, off, 64);
  const float d = s * (1.0f / NB);
  f32x4 o;
  #pragma unroll
  for (int j = 0; j < 4; j++) o[j] = (v[j] >= thr) ? v[j] / d : 0.f;
  p0[lane] = o;
}

// ---------------- K2b: exact recompute of boundary-ambiguous rows -----------
__global__ __launch_bounds__(256) void refine(
    const float* __restrict__ x, const float* __restrict__ gw,
    const float* __restrict__ gb, const int* __restrict__ flags,
    float* __restrict__ part)
{
  const int lane = threadIdx.x & 63;
  const int row  = blockIdx.x * 4 + (threadIdx.x >> 6);
  if (!flags[row]) return;

  f32x4 acc0 = (f32x4)0.f, acc1 = (f32x4)0.f;
  const float* xp = &x[(size_t)row * DIN];
  #pragma unroll 8
  for (int k = 0; k < 1024; k++){
    const float xv = xp[k];
    const f32x4 wv = *(const f32x4*)&gw[(size_t)k * NB + lane * 4];
    #pragma unroll
    for (int j = 0; j < 4; j++) acc0[j] = fmaf(xv, wv[j], acc0[j]);
  }
  #pragma unroll 8
  for (int k = 1024; k < 2048; k++){
    const float xv = xp[k];
    const f32x4 wv = *(const f32x4*)&gw[(size_t)k * NB + lane * 4];
    #pragma unroll
    for (int j = 0; j < 4; j++) acc1[j] = fmaf(xv, wv[j], acc1[j]);
  }
  const f32x4 gbv = *(const f32x4*)&gb[lane * 4];
  f32x4 v;
  #pragma unroll
  for (int j = 0; j < 4; j++) v[j] = acc0[j] + acc1[j] + gbv[j];

  const float NEG = -3.402823466e38f;
  float w0 = v[0], w1 = v[1], w2 = v[2], w3 = v[3];
  float thr = 0.f;
  for (int it = 0; it < KSEL; it++){
    float lm = fmaxf(fmaxf(w0, w1), fmaxf(w2, w3));
    float wm = lm;
    #pragma unroll
    for (int off = 32; off; off >>= 1) wm = fmaxf(wm, __shfl_xor(wm, off, 64));
    unsigned long long ball = __ballot(lm == wm);
    int first = __ffsll(ball) - 1;
    if (lane == first){
      if      (w0 == wm) w0 = NEG;
      else if (w1 == wm) w1 = NEG;
      else if (w2 == wm) w2 = NEG;
      else               w3 = NEG;
    }
    thr = wm;
  }
  float s = 0.f;
  #pragma unroll
  for (int j = 0; j < 4; j++) s += (v[j] >= thr) ? v[j] : 0.f;
  #pragma unroll
  for (int off = 32; off; off >>= 1) s += __shfl_xor(s, off, 64);
  const float d = s * (1.0f / NB);
  f32x4 o;
  #pragma unroll
  for (int j = 0; j < 4; j++) o[j] = (v[j] >= thr) ? v[j] / d : 0.f;
  *(f32x4*)&part[(size_t)row * NB + lane * 4] = o;
}

// ---------------- K3: gated main GEMM, bf16 MFMA 16x16x32 -------------------
// A staged from x f32 (gate-mul + single cvt; no bf16 unpack). BK=64.
__global__ __launch_bounds__(256) void main_gemm(
    const float* __restrict__ x,
    const unsigned short* __restrict__ wt,
    const float* __restrict__ g,
    const float* __restrict__ bias,
    float* __restrict__ out)
{
  __shared__ unsigned short xa[128][72];   // [row][k] gated bf16, +8 pad
  __shared__ unsigned short wb[128][72];   // [n][k]   bf16 (W^T), +8 pad
  __shared__ float gl[128 * 17];           // gates [row][p], stride 17

  const int q    = blockIdx.x;             // output block col 0..15
  const int b0   = blockIdx.y * 128;       // batch row tile
  const int t    = threadIdx.x;
  const int lane = t & 63;
  const int wid  = t >> 6;
  const int wr   = (wid >> 1) * 64;
  const int wc   = (wid & 1) * 64;
  const int l15  = lane & 15;
  const int l4   = lane >> 4;

  for (int e = t; e < 128 * 16; e += 256){
    const int r = e >> 4, p = e & 15;
    gl[r * 17 + p] = g[(size_t)(b0 + r) * NB + p * 16 + q];
  }

  f32x4 acc[4][4];
  #pragma unroll
  for (int m = 0; m < 4; m++)
    #pragma unroll
    for (int n = 0; n < 4; n++) acc[m][n] = (f32x4)0.0f;

  const int row_s = t >> 1;
  const int half  = t & 1;

  for (int kp = 0; kp < 32; kp++){         // 32 K-slices of 64 (p = kp>>1)
    const int p = kp >> 1;
    __syncthreads();
    { // stage gated A: x (f32) * gate -> bf16
      const float gate = gl[row_s * 17 + p];
      const float* src = &x[(size_t)(b0 + row_s) * DIN + kp * 64 + half * 32];
      unsigned short* dst = &xa[row_s][half * 32];
      #pragma unroll
      for (int c = 0; c < 4; c++){
        f32x4 a0 = *(const f32x4*)(src + c * 8);
        f32x4 a1 = *(const f32x4*)(src + c * 8 + 4);
        u16x8 o;
        #pragma unroll
        for (int j = 0; j < 4; j++){
          o[j]     = f2bf_c(a0[j] * gate);
          o[4 + j] = f2bf_c(a1[j] * gate);
        }
        *(u16x8*)(dst + c * 8) = o;
      }
    }
    { // stage B: W^T tile copy
      const unsigned short* src = &wt[(size_t)(q * 128 + row_s) * DIN + kp * 64 + half * 32];
      unsigned short* dst = &wb[row_s][half * 32];
      #pragma unroll
      for (int c = 0; c < 4; c++)
        *(u16x8*)(dst + c * 8) = *(const u16x8*)(src + c * 8);
    }
    __syncthreads();
    #pragma unroll
    for (int ksi = 0; ksi < 2; ksi++){
      const int kk = ksi * 32 + l4 * 8;
      bf16x8 a[4], b[4];
      #pragma unroll
      for (int m = 0; m < 4; m++)
        a[m] = *(const bf16x8*)&xa[wr + m * 16 + l15][kk];
      #pragma unroll
      for (int n = 0; n < 4; n++)
        b[n] = *(const bf16x8*)&wb[wc + n * 16 + l15][kk];
      #pragma unroll
      for (int m = 0; m < 4; m++)
        #pragma unroll
        for (int n = 0; n < 4; n++)
          acc[m][n] = __builtin_amdgcn_mfma_f32_16x16x32_bf16(a[m], b[n], acc[m][n], 0, 0, 0);
    }
  }

  #pragma unroll
  for (int n = 0; n < 4; n++){
    const int col = q * 128 + wc + n * 16 + l15;
    const float bv = bias[col];
    #pragma unroll
    for (int m = 0; m < 4; m++){
      #pragma unroll
      for (int r = 0; r < 4; r++){
        const int row = b0 + wr + m * 16 + l4 * 4 + r;
        out[(size_t)row * DOUT + col] = acc[m][n][r] + bv;
      }
    }
  }
}

// ---------------- launch -----------------------------------------------------
extern "C" void kernel_launch(void* const* d_in, const int* in_sizes, int n_in,
                              void* d_out, int out_size, void* d_ws, size_t ws_size,
                              hipStream_t stream)
{
  const float* x    = (const float*)d_in[0];
  const float* w    = (const float*)d_in[1];
  const float* bias = (const float*)d_in[2];
  const float* gw   = (const float*)d_in[3];
  const float* gb   = (const float*)d_in[4];
  float* out = (float*)d_out;

  // ws layout: [0,32M) part 4 splits (split 0 becomes final gates),
  //            [32M,40M) W^T bf16, [40M,41M) g_hi^T, [41M,42M) g_lo^T, [42M,..) flags
  char* wsb = (char*)d_ws;
  float*          part = (float*)wsb;
  unsigned short* wtb  = (unsigned short*)(wsb + (size_t)32 * 1024 * 1024);
  unsigned short* ghiT = (unsigned short*)(wsb + (size_t)40 * 1024 * 1024);
  unsigned short* gloT = (unsigned short*)(wsb + (size_t)41 * 1024 * 1024);
  int*            flg  = (int*)           (wsb + (size_t)42 * 1024 * 1024);

  conv_wt  <<<dim3(DIN / 64, DOUT / 64), 256, 0, stream>>>(w, wtb);
  conv_gwt <<<dim3(DIN / 64, NB / 64),   256, 0, stream>>>(gw, ghiT, gloT);
  gate_flip<<<dim3(NB / 64, BATCH / 256, 4), 256, 0, stream>>>(x, ghiT, gloT, part);
  topk     <<<BATCH / 4, 256, 0, stream>>>(part, gb, flg);
  refine   <<<BATCH / 4, 256, 0, stream>>>(x, gw, gb, flg, part);
  main_gemm<<<dim3(16, BATCH / 128), 256, 0, stream>>>(x, wtb, part, bias, out);
}

// Round 7
// 332.157 us; speedup vs baseline: 1.0328x; 1.0328x over previous
//
#include <hip/hip_runtime.h>
#include <hip/hip_bf16.h>
#include <stdint.h>

#define BATCH  8192
#define DIN    2048
#define DOUT   2048
#define NB     256
#define KSEL   26      // ceil(0.1*256)
#define GDELTA 1e-4f   // top-k boundary refine threshold

typedef __attribute__((ext_vector_type(2))) float f32x2;
typedef __attribute__((ext_vector_type(4))) float f32x4;
typedef __attribute__((ext_vector_type(16))) float f32x16;
typedef __attribute__((ext_vector_type(8))) __bf16 bf16x8;
typedef __attribute__((ext_vector_type(8))) unsigned short u16x8;
typedef __attribute__((ext_vector_type(4))) unsigned short u16x4;

__device__ __forceinline__ float bf2f(unsigned short u){
  union { unsigned int i; float f; } v; v.i = ((unsigned int)u) << 16; return v.f;
}
__device__ __forceinline__ unsigned short f2bf(float f){
  union { float f; unsigned int i; } v; v.f = f;
  unsigned int x = v.i;
  return (unsigned short)((x + 0x7FFFu + ((x >> 16) & 1u)) >> 16);  // RNE
}
__device__ __forceinline__ unsigned short f2bf_c(float f){
  __bf16 b = (__bf16)f;
  union { __bf16 b; unsigned short u; } v; v.b = b; return v.u;
}

// ---------------- K0b: W -> W^T bf16 (wt[n][k] = W[k][n]) ----------------
// NOTE: launched AFTER refine — its output region overlays ghiT/gloT/flags,
// which are dead by then.
__global__ __launch_bounds__(256) void conv_wt(const float* __restrict__ w, unsigned short* __restrict__ wt)
{
  __shared__ float tl[64][65];
  const int k0 = blockIdx.x * 64;
  const int n0 = blockIdx.y * 64;
  const int c  = threadIdx.x & 63;
  const int r4 = threadIdx.x >> 6;
  #pragma unroll
  for (int i = 0; i < 16; i++){
    const int r = r4 * 16 + i;
    tl[r][c] = w[(size_t)(k0 + r) * DOUT + n0 + c];
  }
  __syncthreads();
  #pragma unroll
  for (int i = 0; i < 16; i++){
    const int n = r4 * 16 + i;
    wt[(size_t)(n0 + n) * DIN + k0 + c] = f2bf(tl[c][n]);
  }
}

// ---------------- K0c: gw -> transposed hi/lo bf16 split --------------------
__global__ __launch_bounds__(256) void conv_gwt(const float* __restrict__ gw,
    unsigned short* __restrict__ ghiT, unsigned short* __restrict__ gloT)
{
  __shared__ float tl[64][65];
  const int k0 = blockIdx.x * 64;
  const int n0 = blockIdx.y * 64;
  const int c  = threadIdx.x & 63;
  const int r4 = threadIdx.x >> 6;
  #pragma unroll
  for (int i = 0; i < 16; i++){
    const int r = r4 * 16 + i;
    tl[r][c] = gw[(size_t)(k0 + r) * NB + n0 + c];
  }
  __syncthreads();
  #pragma unroll
  for (int i = 0; i < 16; i++){
    const int n = r4 * 16 + i;
    const float v = tl[c][n];
    const unsigned short h = f2bf_c(v);
    ghiT[(size_t)(n0 + n) * DIN + k0 + c] = h;
    gloT[(size_t)(n0 + n) * DIN + k0 + c] = f2bf_c(v - bf2f(h));
  }
}

// ---------------- K1: FLIPPED gate GEMM via bf16 MFMA -----------------------
// part^T = g^T (M=256 c) x x^T (N=8192 b). Grid (64 b-tiles, 4 c-tiles, 2 ks)
// with blockIdx.x = b so the 4 c-mates (same x rows) land on the same XCD ->
// x HBM-fetched ~once. Two launches: ksbase=0 (store), ksbase=2 (accumulate)
// into 2 part splits. Block 256 thr = 4 waves (2 c-waves x 2 b-waves), wave
// tile 32c x 64b, K-step 32, LDS dbuf for g hi/lo only; x loaded per-lane
// from global and converted hi/lo bf16 in regs (B-frag layout == row-major x).
// 3 MFMA terms: gh*xh + gl*xh + gh*xl (sigma ~3.6e-6 vs exact; boundary rows
// refined exactly). c0==0/cw==0 waves also emit xb = bf16(x) for main_gemm.
template<bool ACC>
__global__ __launch_bounds__(256) void gate_flip(
    const float* __restrict__ x,
    const unsigned short* __restrict__ ghiT,
    const unsigned short* __restrict__ gloT,
    float* __restrict__ part,
    unsigned short* __restrict__ xb,
    int ksbase)
{
  __shared__ unsigned short Ah[2][64][40], Al[2][64][40];   // 20.5 KB

  const int b0   = blockIdx.x * 128;   // b-tile (batch block)
  const int c0   = blockIdx.y * 64;    // c-tile (gate col block)
  const int s    = blockIdx.z;         // split slot 0/1
  const int k0   = (ksbase + s) * 512;
  const int t    = threadIdx.x;
  const int lane = t & 63;
  const int wv   = t >> 6;
  const int cw   = wv >> 1;            // c-wave 0/1 -> cols c0+cw*32
  const int bw   = wv & 1;             // b-wave 0/1 -> rows b0+bw*64
  const int l31  = lane & 31;
  const int lk   = (lane >> 5) * 8;

  const bool emit = (blockIdx.y == 0) && (cw == 0);

  // A staging map
  const int sc = t >> 2;
  const int sk = (t & 3) * 8;

  f32x16 acc[2];
  acc[0] = (f32x16)0.f; acc[1] = (f32x16)0.f;

  auto STAGE = [&](int bb, int kc){
    *(u16x8*)&Ah[bb][sc][sk] = *(const u16x8*)&ghiT[(size_t)(c0 + sc) * DIN + kc + sk];
    *(u16x8*)&Al[bb][sc][sk] = *(const u16x8*)&gloT[(size_t)(c0 + sc) * DIN + kc + sk];
  };

  auto LOADB = [&](f32x4 (&xr)[2][2][2], int kc){   // [n][kh][half]
    #pragma unroll
    for (int n = 0; n < 2; n++){
      const size_t rowb = (size_t)(b0 + bw * 64 + n * 32 + l31) * DIN;
      #pragma unroll
      for (int kh = 0; kh < 2; kh++){
        const float* xp = &x[rowb + kc + kh * 16 + lk];
        xr[n][kh][0] = *(const f32x4*)xp;
        xr[n][kh][1] = *(const f32x4*)(xp + 4);
      }
    }
  };

  auto COMP = [&](const f32x4 (&xr)[2][2][2], int bb, int kc){
    bf16x8 bhf[2][2], blf[2][2];
    #pragma unroll
    for (int n = 0; n < 2; n++)
      #pragma unroll
      for (int kh = 0; kh < 2; kh++){
        bf16x8 h, l;
        #pragma unroll
        for (int q = 0; q < 2; q++)
          #pragma unroll
          for (int j = 0; j < 4; j++){
            const float v = xr[n][kh][q][j];
            const __bf16 hb = (__bf16)v;
            h[q * 4 + j] = hb;
            l[q * 4 + j] = (__bf16)(v - (float)hb);
          }
        bhf[n][kh] = h; blf[n][kh] = l;
      }
    if (emit){
      #pragma unroll
      for (int n = 0; n < 2; n++){
        const size_t rowb = (size_t)(b0 + bw * 64 + n * 32 + l31) * DIN;
        #pragma unroll
        for (int kh = 0; kh < 2; kh++)
          *(u16x8*)&xb[rowb + kc + kh * 16 + lk] = *(u16x8*)&bhf[n][kh];
      }
    }
    #pragma unroll
    for (int kh = 0; kh < 2; kh++){
      const int ko = kh * 16 + lk;
      const bf16x8 ah = *(const bf16x8*)&Ah[bb][cw * 32 + l31][ko];
      const bf16x8 al = *(const bf16x8*)&Al[bb][cw * 32 + l31][ko];
      #pragma unroll
      for (int n = 0; n < 2; n++){
        acc[n] = __builtin_amdgcn_mfma_f32_32x32x16_bf16(ah, bhf[n][kh], acc[n], 0, 0, 0);
        acc[n] = __builtin_amdgcn_mfma_f32_32x32x16_bf16(al, bhf[n][kh], acc[n], 0, 0, 0);
        acc[n] = __builtin_amdgcn_mfma_f32_32x32x16_bf16(ah, blf[n][kh], acc[n], 0, 0, 0);
      }
    }
  };

  f32x4 xrA[2][2][2], xrB[2][2][2];
  LOADB(xrA, k0);
  STAGE(0, k0);
  __syncthreads();
  #pragma unroll 1
  for (int it = 0; it < 8; it++){
    const int kc = k0 + it * 64;
    LOADB(xrB, kc + 32);
    STAGE(1, kc + 32);
    COMP(xrA, 0, kc);
    __syncthreads();
    if (it < 7){
      LOADB(xrA, kc + 64);
      STAGE(0, kc + 64);
    }
    COMP(xrB, 1, kc + 32);
    __syncthreads();
  }

  // C/D 32x32: col(lane&31)=b, row(reg) = (r&3)+8*(r>>2)+4*(lane>>5) = c
  float* dst = part + (size_t)s * BATCH * NB;
  #pragma unroll
  for (int n = 0; n < 2; n++){
    const int brow = b0 + bw * 64 + n * 32 + l31;
    #pragma unroll
    for (int r = 0; r < 16; r++){
      const int ccol = c0 + cw * 32 + (r & 3) + 8 * (r >> 2) + 4 * (lane >> 5);
      if (ACC) dst[(size_t)brow * NB + ccol] += acc[n][r];
      else     dst[(size_t)brow * NB + ccol]  = acc[n][r];
    }
  }
}

// ---------------- K2: sum 2 partials, top-26 + renorm + boundary flag -------
__global__ __launch_bounds__(256) void topk(float* __restrict__ part,
    const float* __restrict__ gb, int* __restrict__ flags)
{
  const int lane = threadIdx.x & 63;
  const int row  = blockIdx.x * 4 + (threadIdx.x >> 6);
  f32x4* p0 = (f32x4*)&part[(size_t)row * NB];
  const f32x4* p1 = (const f32x4*)&part[(size_t)(BATCH + row) * NB];
  const f32x4* gbv = (const f32x4*)gb;
  f32x4 v = p0[lane] + p1[lane] + gbv[lane];

  const float NEG = -3.402823466e38f;
  float w0 = v[0], w1 = v[1], w2 = v[2], w3 = v[3];
  float thr = 0.f, nxt = 0.f;
  for (int it = 0; it < KSEL + 1; it++){
    float lm = fmaxf(fmaxf(w0, w1), fmaxf(w2, w3));
    float wm = lm;
    #pragma unroll
    for (int off = 32; off; off >>= 1) wm = fmaxf(wm, __shfl_xor(wm, off, 64));
    unsigned long long ball = __ballot(lm == wm);
    int first = __ffsll(ball) - 1;
    if (lane == first){
      if      (w0 == wm) w0 = NEG;
      else if (w1 == wm) w1 = NEG;
      else if (w2 == wm) w2 = NEG;
      else               w3 = NEG;
    }
    if (it < KSEL) thr = wm; else nxt = wm;
  }
  if (lane == 0) flags[row] = (thr - nxt < GDELTA) ? 1 : 0;

  float s = 0.f;
  #pragma unroll
  for (int j = 0; j < 4; j++) s += (v[j] >= thr) ? v[j] : 0.f;
  #pragma unroll
  for (int off = 32; off; off >>= 1) s += __shfl_xor(s, off, 64);
  const float d = s * (1.0f / NB);
  f32x4 o;
  #pragma unroll
  for (int j = 0; j < 4; j++) o[j] = (v[j] >= thr) ? v[j] / d : 0.f;
  p0[lane] = o;
}

// ---------------- K2b: exact recompute of boundary-ambiguous rows -----------
__global__ __launch_bounds__(256) void refine(
    const float* __restrict__ x, const float* __restrict__ gw,
    const float* __restrict__ gb, const int* __restrict__ flags,
    float* __restrict__ part)
{
  const int lane = threadIdx.x & 63;
  const int row  = blockIdx.x * 4 + (threadIdx.x >> 6);
  if (!flags[row]) return;

  f32x4 acc0 = (f32x4)0.f, acc1 = (f32x4)0.f;
  const float* xp = &x[(size_t)row * DIN];
  #pragma unroll 8
  for (int k = 0; k < 1024; k++){
    const float xv = xp[k];
    const f32x4 wv = *(const f32x4*)&gw[(size_t)k * NB + lane * 4];
    #pragma unroll
    for (int j = 0; j < 4; j++) acc0[j] = fmaf(xv, wv[j], acc0[j]);
  }
  #pragma unroll 8
  for (int k = 1024; k < 2048; k++){
    const float xv = xp[k];
    const f32x4 wv = *(const f32x4*)&gw[(size_t)k * NB + lane * 4];
    #pragma unroll
    for (int j = 0; j < 4; j++) acc1[j] = fmaf(xv, wv[j], acc1[j]);
  }
  const f32x4 gbv = *(const f32x4*)&gb[lane * 4];
  f32x4 v;
  #pragma unroll
  for (int j = 0; j < 4; j++) v[j] = acc0[j] + acc1[j] + gbv[j];

  const float NEG = -3.402823466e38f;
  float w0 = v[0], w1 = v[1], w2 = v[2], w3 = v[3];
  float thr = 0.f;
  for (int it = 0; it < KSEL; it++){
    float lm = fmaxf(fmaxf(w0, w1), fmaxf(w2, w3));
    float wm = lm;
    #pragma unroll
    for (int off = 32; off; off >>= 1) wm = fmaxf(wm, __shfl_xor(wm, off, 64));
    unsigned long long ball = __ballot(lm == wm);
    int first = __ffsll(ball) - 1;
    if (lane == first){
      if      (w0 == wm) w0 = NEG;
      else if (w1 == wm) w1 = NEG;
      else if (w2 == wm) w2 = NEG;
      else               w3 = NEG;
    }
    thr = wm;
  }
  float s = 0.f;
  #pragma unroll
  for (int j = 0; j < 4; j++) s += (v[j] >= thr) ? v[j] : 0.f;
  #pragma unroll
  for (int off = 32; off; off >>= 1) s += __shfl_xor(s, off, 64);
  const float d = s * (1.0f / NB);
  f32x4 o;
  #pragma unroll
  for (int j = 0; j < 4; j++) o[j] = (v[j] >= thr) ? v[j] / d : 0.f;
  *(f32x4*)&part[(size_t)row * NB + lane * 4] = o;
}

// ---------------- K3: gated main GEMM, bf16 MFMA 16x16x32 -------------------
// R5-measured 134us version: A staged from xb bf16 (unpack + gate + repack).
__global__ __launch_bounds__(256) void main_gemm(
    const unsigned short* __restrict__ xb,
    const unsigned short* __restrict__ wt,
    const float* __restrict__ g,
    const float* __restrict__ bias,
    float* __restrict__ out)
{
  __shared__ unsigned short xa[128][72];   // [row][k] gated bf16, +8 pad
  __shared__ unsigned short wb[128][72];   // [n][k]   bf16 (W^T), +8 pad
  __shared__ float gl[128 * 17];           // gates [row][p], stride 17

  const int q    = blockIdx.x;             // output block col 0..15
  const int b0   = blockIdx.y * 128;       // batch row tile
  const int t    = threadIdx.x;
  const int lane = t & 63;
  const int wid  = t >> 6;
  const int wr   = (wid >> 1) * 64;
  const int wc   = (wid & 1) * 64;
  const int l15  = lane & 15;
  const int l4   = lane >> 4;

  for (int e = t; e < 128 * 16; e += 256){
    const int r = e >> 4, p = e & 15;
    gl[r * 17 + p] = g[(size_t)(b0 + r) * NB + p * 16 + q];
  }

  f32x4 acc[4][4];
  #pragma unroll
  for (int m = 0; m < 4; m++)
    #pragma unroll
    for (int n = 0; n < 4; n++) acc[m][n] = (f32x4)0.0f;

  const int row_s = t >> 1;
  const int half  = t & 1;

  for (int kp = 0; kp < 32; kp++){         // 32 K-slices of 64 (p = kp>>1)
    const int p = kp >> 1;
    __syncthreads();
    { // stage gated A: xb * gate -> bf16
      const float gate = gl[row_s * 17 + p];
      const unsigned short* src = &xb[(size_t)(b0 + row_s) * DIN + kp * 64 + half * 32];
      unsigned short* dst = &xa[row_s][half * 32];
      #pragma unroll
      for (int c = 0; c < 4; c++){
        u16x8 u = *(const u16x8*)(src + c * 8);
        u16x8 o;
        #pragma unroll
        for (int j = 0; j < 8; j++) o[j] = f2bf_c(bf2f(u[j]) * gate);
        *(u16x8*)(dst + c * 8) = o;
      }
    }
    { // stage B: W^T tile copy
      const unsigned short* src = &wt[(size_t)(q * 128 + row_s) * DIN + kp * 64 + half * 32];
      unsigned short* dst = &wb[row_s][half * 32];
      #pragma unroll
      for (int c = 0; c < 4; c++)
        *(u16x8*)(dst + c * 8) = *(const u16x8*)(src + c * 8);
    }
    __syncthreads();
    #pragma unroll
    for (int ksi = 0; ksi < 2; ksi++){
      const int kk = ksi * 32 + l4 * 8;
      bf16x8 a[4], b[4];
      #pragma unroll
      for (int m = 0; m < 4; m++)
        a[m] = *(const bf16x8*)&xa[wr + m * 16 + l15][kk];
      #pragma unroll
      for (int n = 0; n < 4; n++)
        b[n] = *(const bf16x8*)&wb[wc + n * 16 + l15][kk];
      #pragma unroll
      for (int m = 0; m < 4; m++)
        #pragma unroll
        for (int n = 0; n < 4; n++)
          acc[m][n] = __builtin_amdgcn_mfma_f32_16x16x32_bf16(a[m], b[n], acc[m][n], 0, 0, 0);
    }
  }

  #pragma unroll
  for (int n = 0; n < 4; n++){
    const int col = q * 128 + wc + n * 16 + l15;
    const float bv = bias[col];
    #pragma unroll
    for (int m = 0; m < 4; m++){
      #pragma unroll
      for (int r = 0; r < 4; r++){
        const int row = b0 + wr + m * 16 + l4 * 4 + r;
        out[(size_t)row * DOUT + col] = acc[m][n][r] + bv;
      }
    }
  }
}

// ---------------- launch -----------------------------------------------------
extern "C" void kernel_launch(void* const* d_in, const int* in_sizes, int n_in,
                              void* d_out, int out_size, void* d_ws, size_t ws_size,
                              hipStream_t stream)
{
  const float* x    = (const float*)d_in[0];
  const float* w    = (const float*)d_in[1];
  const float* bias = (const float*)d_in[2];
  const float* gw   = (const float*)d_in[3];
  const float* gb   = (const float*)d_in[4];
  float* out = (float*)d_out;

  // ws layout (56 MiB total, proven budget):
  //   [0,16M)  part: 2 f32 splits (split 0 becomes final gates)
  //   [16,48M) xb: bf16(x), emitted by gate_flip, consumed by main_gemm
  //   [48,56M) phase A: ghiT@48M, gloT@49M, flags@50M  (dead after refine)
  //            phase B: wtb (8 MiB, written by conv_wt AFTER refine)
  char* wsb = (char*)d_ws;
  float*          part = (float*)wsb;
  unsigned short* xbb  = (unsigned short*)(wsb + (size_t)16 * 1024 * 1024);
  unsigned short* ghiT = (unsigned short*)(wsb + (size_t)48 * 1024 * 1024);
  unsigned short* gloT = (unsigned short*)(wsb + (size_t)49 * 1024 * 1024);
  int*            flg  = (int*)           (wsb + (size_t)50 * 1024 * 1024);
  unsigned short* wtb  = (unsigned short*)(wsb + (size_t)48 * 1024 * 1024);

  conv_gwt        <<<dim3(DIN / 64, NB / 64), 256, 0, stream>>>(gw, ghiT, gloT);
  gate_flip<false><<<dim3(BATCH / 128, NB / 64, 2), 256, 0, stream>>>(x, ghiT, gloT, part, xbb, 0);
  gate_flip<true> <<<dim3(BATCH / 128, NB / 64, 2), 256, 0, stream>>>(x, ghiT, gloT, part, xbb, 2);
  topk            <<<BATCH / 4, 256, 0, stream>>>(part, gb, flg);
  refine          <<<BATCH / 4, 256, 0, stream>>>(x, gw, gb, flg, part);
  conv_wt         <<<dim3(DIN / 64, DOUT / 64), 256, 0, stream>>>(w, wtb);
  main_gemm       <<<dim3(16, BATCH / 128), 256, 0, stream>>>(xbb, wtb, part, bias, out);
}

// Round 8
// 256.977 us; speedup vs baseline: 1.3350x; 1.2926x over previous
//
#include <hip/hip_runtime.h>
#include <hip/hip_bf16.h>
#include <stdint.h>

#define BATCH  8192
#define DIN    2048
#define DOUT   2048
#define NB     256
#define KSEL   26      // ceil(0.1*256)
#define GDELTA 1e-4f   // top-k boundary refine threshold

typedef __attribute__((ext_vector_type(2))) float f32x2;
typedef __attribute__((ext_vector_type(4))) float f32x4;
typedef __attribute__((ext_vector_type(16))) float f32x16;
typedef __attribute__((ext_vector_type(8))) __bf16 bf16x8;
typedef __attribute__((ext_vector_type(8))) unsigned short u16x8;
typedef __attribute__((ext_vector_type(4))) unsigned short u16x4;

__device__ __forceinline__ float bf2f(unsigned short u){
  union { unsigned int i; float f; } v; v.i = ((unsigned int)u) << 16; return v.f;
}
__device__ __forceinline__ unsigned short f2bf(float f){
  union { float f; unsigned int i; } v; v.f = f;
  unsigned int x = v.i;
  return (unsigned short)((x + 0x7FFFu + ((x >> 16) & 1u)) >> 16);  // RNE
}
__device__ __forceinline__ unsigned short f2bf_c(float f){
  __bf16 b = (__bf16)f;
  union { __bf16 b; unsigned short u; } v; v.b = b; return v.u;
}

// ---------------- K0b: W -> W^T bf16 (wt[n][k] = W[k][n]) ----------------
// Launched AFTER refine — output overlays ghiT/gloT/flags (dead by then).
__global__ __launch_bounds__(256) void conv_wt(const float* __restrict__ w, unsigned short* __restrict__ wt)
{
  __shared__ float tl[64][65];
  const int k0 = blockIdx.x * 64;
  const int n0 = blockIdx.y * 64;
  const int c  = threadIdx.x & 63;
  const int r4 = threadIdx.x >> 6;
  #pragma unroll
  for (int i = 0; i < 16; i++){
    const int r = r4 * 16 + i;
    tl[r][c] = w[(size_t)(k0 + r) * DOUT + n0 + c];
  }
  __syncthreads();
  #pragma unroll
  for (int i = 0; i < 16; i++){
    const int n = r4 * 16 + i;
    wt[(size_t)(n0 + n) * DIN + k0 + c] = f2bf(tl[c][n]);
  }
}

// ---------------- K0c: gw -> transposed hi/lo bf16 split --------------------
__global__ __launch_bounds__(256) void conv_gwt(const float* __restrict__ gw,
    unsigned short* __restrict__ ghiT, unsigned short* __restrict__ gloT)
{
  __shared__ float tl[64][65];
  const int k0 = blockIdx.x * 64;
  const int n0 = blockIdx.y * 64;
  const int c  = threadIdx.x & 63;
  const int r4 = threadIdx.x >> 6;
  #pragma unroll
  for (int i = 0; i < 16; i++){
    const int r = r4 * 16 + i;
    tl[r][c] = gw[(size_t)(k0 + r) * NB + n0 + c];
  }
  __syncthreads();
  #pragma unroll
  for (int i = 0; i < 16; i++){
    const int n = r4 * 16 + i;
    const float v = tl[c][n];
    const unsigned short h = f2bf_c(v);
    ghiT[(size_t)(n0 + n) * DIN + k0 + c] = h;
    gloT[(size_t)(n0 + n) * DIN + k0 + c] = f2bf_c(v - bf2f(h));
  }
}

// ---------------- K1: gate GEMM, both operands LDS-staged, 3-term MFMA ------
// part[b][c] (+2 K-splits) = x @ gw via x_hi*g_hi + x_lo*g_hi + x_hi*g_lo.
// Block 64b x 128c, 4 waves (wave 32b x 64c, m2 x n4 of 16x16x32), BK=64.
// Linear 128B LDS rows + XOR swizzle (chunk ^= row&7) -> ~conflict-free frag
// reads. T14 staging: global loads for step s+1 issued right after barrier.
// Grid (128 b, 2 c, 2 ks) = 512 blocks (2/CU). c==0 blocks emit xb = bf16(x).
__global__ __launch_bounds__(256) void gate_v2(
    const float* __restrict__ x,
    const unsigned short* __restrict__ ghiT,
    const unsigned short* __restrict__ gloT,
    float* __restrict__ part,
    unsigned short* __restrict__ xb)
{
  __shared__ unsigned short Axh[64][64], Axl[64][64];    // 16 KB
  __shared__ unsigned short Bgh[128][64], Bgl[128][64];  // 32 KB

  const int b0   = blockIdx.x * 64;
  const int c0   = blockIdx.y * 128;
  const int ks   = blockIdx.z;
  const int k0   = ks * 1024;
  const int t    = threadIdx.x;
  const int lane = t & 63;
  const int wv   = t >> 6;
  const int bw   = wv & 1;           // b-wave: rows bw*32
  const int cw   = wv >> 1;          // c-wave: cols cw*64
  const int l15  = lane & 15;
  const int l4   = lane >> 4;
  const bool emit = (blockIdx.y == 0);

  // staging maps
  const int ar = t >> 2;             // A row 0..63
  const int ak = (t & 3) * 16;       // A k base (16 f32)
  const int br = t >> 1;             // B row 0..127
  const int bk = (t & 1) * 32;       // B k base (32 u16)

  f32x4 acc[2][4];
  #pragma unroll
  for (int m = 0; m < 2; m++)
    #pragma unroll
    for (int n = 0; n < 4; n++) acc[m][n] = (f32x4)0.0f;

  // hoisted swizzled read offsets (u16 units)
  int aoff[2][2], boff[2][4];
  #pragma unroll
  for (int ksi = 0; ksi < 2; ksi++){
    const int chunk = ksi * 4 + l4;
    #pragma unroll
    for (int m = 0; m < 2; m++){
      const int row = bw * 32 + m * 16 + l15;
      aoff[ksi][m] = row * 64 + ((chunk ^ (row & 7)) << 3);
    }
    #pragma unroll
    for (int n = 0; n < 4; n++){
      const int row = cw * 64 + n * 16 + l15;
      boff[ksi][n] = row * 64 + ((chunk ^ (row & 7)) << 3);
    }
  }

  f32x4 xa[4];
  u16x8 gh[4], glo[4];

  auto LOAD = [&](int kb){
    const float* xp = &x[(size_t)(b0 + ar) * DIN + kb + ak];
    #pragma unroll
    for (int j = 0; j < 4; j++) xa[j] = ((const f32x4*)xp)[j];
    const unsigned short* hp = &ghiT[(size_t)(c0 + br) * DIN + kb + bk];
    const unsigned short* lp = &gloT[(size_t)(c0 + br) * DIN + kb + bk];
    #pragma unroll
    for (int j = 0; j < 4; j++){ gh[j] = ((const u16x8*)hp)[j]; glo[j] = ((const u16x8*)lp)[j]; }
  };

  auto WRITE = [&](int kb){
    const int asw = ar & 7;
    #pragma unroll
    for (int h = 0; h < 2; h++){
      u16x8 hi, lo;
      #pragma unroll
      for (int j = 0; j < 8; j++){
        const float v = xa[h * 2 + (j >> 2)][j & 3];
        const __bf16 hb = (__bf16)v;
        union { __bf16 b; unsigned short u; } uh; uh.b = hb;
        hi[j] = uh.u;
        lo[j] = f2bf_c(v - (float)hb);
      }
      const int c8 = (((ak >> 3) + h) ^ asw) << 3;
      *(u16x8*)&Axh[ar][c8] = hi;
      *(u16x8*)&Axl[ar][c8] = lo;
      if (emit) *(u16x8*)&xb[(size_t)(b0 + ar) * DIN + kb + ak + h * 8] = hi;
    }
    const int bsw = br & 7;
    #pragma unroll
    for (int j = 0; j < 4; j++){
      const int c8 = (((bk >> 3) + j) ^ bsw) << 3;
      *(u16x8*)&Bgh[br][c8] = gh[j];
      *(u16x8*)&Bgl[br][c8] = glo[j];
    }
  };

  const unsigned short* Ah0 = &Axh[0][0];
  const unsigned short* Al0 = &Axl[0][0];
  const unsigned short* Bh0 = &Bgh[0][0];
  const unsigned short* Bl0 = &Bgl[0][0];

  LOAD(k0);
  #pragma unroll 1
  for (int s = 0; s < 16; s++){
    const int kb = k0 + s * 64;
    __syncthreads();                 // LDS free (prev compute done)
    WRITE(kb);
    __syncthreads();
    if (s < 15) LOAD(kb + 64);       // latency hides under compute
    #pragma unroll
    for (int ksi = 0; ksi < 2; ksi++){
      bf16x8 ah[2], al[2], bh[4], bl[4];
      #pragma unroll
      for (int m = 0; m < 2; m++){
        ah[m] = *(const bf16x8*)&Ah0[aoff[ksi][m]];
        al[m] = *(const bf16x8*)&Al0[aoff[ksi][m]];
      }
      #pragma unroll
      for (int n = 0; n < 4; n++){
        bh[n] = *(const bf16x8*)&Bh0[boff[ksi][n]];
        bl[n] = *(const bf16x8*)&Bl0[boff[ksi][n]];
      }
      #pragma unroll
      for (int m = 0; m < 2; m++)
        #pragma unroll
        for (int n = 0; n < 4; n++){
          acc[m][n] = __builtin_amdgcn_mfma_f32_16x16x32_bf16(ah[m], bh[n], acc[m][n], 0, 0, 0);
          acc[m][n] = __builtin_amdgcn_mfma_f32_16x16x32_bf16(al[m], bh[n], acc[m][n], 0, 0, 0);
          acc[m][n] = __builtin_amdgcn_mfma_f32_16x16x32_bf16(ah[m], bl[n], acc[m][n], 0, 0, 0);
        }
    }
  }

  // C/D 16x16: col = lane&15 (c), row = (lane>>4)*4 + r (b)
  float* dst = part + (size_t)ks * BATCH * NB;
  #pragma unroll
  for (int m = 0; m < 2; m++){
    const int brow = b0 + bw * 32 + m * 16 + l4 * 4;
    #pragma unroll
    for (int n = 0; n < 4; n++){
      const int ccol = c0 + cw * 64 + n * 16 + l15;
      #pragma unroll
      for (int r = 0; r < 4; r++)
        dst[(size_t)(brow + r) * NB + ccol] = acc[m][n][r];
    }
  }
}

// ---------------- K2: sum 2 partials, top-26 + renorm + boundary flag -------
__global__ __launch_bounds__(256) void topk(float* __restrict__ part,
    const float* __restrict__ gb, int* __restrict__ flags)
{
  const int lane = threadIdx.x & 63;
  const int row  = blockIdx.x * 4 + (threadIdx.x >> 6);
  f32x4* p0 = (f32x4*)&part[(size_t)row * NB];
  const f32x4* p1 = (const f32x4*)&part[(size_t)(BATCH + row) * NB];
  const f32x4* gbv = (const f32x4*)gb;
  f32x4 v = p0[lane] + p1[lane] + gbv[lane];

  const float NEG = -3.402823466e38f;
  float w0 = v[0], w1 = v[1], w2 = v[2], w3 = v[3];
  float thr = 0.f, nxt = 0.f;
  for (int it = 0; it < KSEL + 1; it++){
    float lm = fmaxf(fmaxf(w0, w1), fmaxf(w2, w3));
    float wm = lm;
    #pragma unroll
    for (int off = 32; off; off >>= 1) wm = fmaxf(wm, __shfl_xor(wm, off, 64));
    unsigned long long ball = __ballot(lm == wm);
    int first = __ffsll(ball) - 1;
    if (lane == first){
      if      (w0 == wm) w0 = NEG;
      else if (w1 == wm) w1 = NEG;
      else if (w2 == wm) w2 = NEG;
      else               w3 = NEG;
    }
    if (it < KSEL) thr = wm; else nxt = wm;
  }
  if (lane == 0) flags[row] = (thr - nxt < GDELTA) ? 1 : 0;

  float s = 0.f;
  #pragma unroll
  for (int j = 0; j < 4; j++) s += (v[j] >= thr) ? v[j] : 0.f;
  #pragma unroll
  for (int off = 32; off; off >>= 1) s += __shfl_xor(s, off, 64);
  const float d = s * (1.0f / NB);
  f32x4 o;
  #pragma unroll
  for (int j = 0; j < 4; j++) o[j] = (v[j] >= thr) ? v[j] / d : 0.f;
  p0[lane] = o;
}

// ---------------- K2b: exact recompute of boundary-ambiguous rows -----------
__global__ __launch_bounds__(256) void refine(
    const float* __restrict__ x, const float* __restrict__ gw,
    const float* __restrict__ gb, const int* __restrict__ flags,
    float* __restrict__ part)
{
  const int lane = threadIdx.x & 63;
  const int row  = blockIdx.x * 4 + (threadIdx.x >> 6);
  if (!flags[row]) return;

  f32x4 acc0 = (f32x4)0.f, acc1 = (f32x4)0.f;
  const float* xp = &x[(size_t)row * DIN];
  #pragma unroll 8
  for (int k = 0; k < 1024; k++){
    const float xv = xp[k];
    const f32x4 wv = *(const f32x4*)&gw[(size_t)k * NB + lane * 4];
    #pragma unroll
    for (int j = 0; j < 4; j++) acc0[j] = fmaf(xv, wv[j], acc0[j]);
  }
  #pragma unroll 8
  for (int k = 1024; k < 2048; k++){
    const float xv = xp[k];
    const f32x4 wv = *(const f32x4*)&gw[(size_t)k * NB + lane * 4];
    #pragma unroll
    for (int j = 0; j < 4; j++) acc1[j] = fmaf(xv, wv[j], acc1[j]);
  }
  const f32x4 gbv = *(const f32x4*)&gb[lane * 4];
  f32x4 v;
  #pragma unroll
  for (int j = 0; j < 4; j++) v[j] = acc0[j] + acc1[j] + gbv[j];

  const float NEG = -3.402823466e38f;
  float w0 = v[0], w1 = v[1], w2 = v[2], w3 = v[3];
  float thr = 0.f;
  for (int it = 0; it < KSEL; it++){
    float lm = fmaxf(fmaxf(w0, w1), fmaxf(w2, w3));
    float wm = lm;
    #pragma unroll
    for (int off = 32; off; off >>= 1) wm = fmaxf(wm, __shfl_xor(wm, off, 64));
    unsigned long long ball = __ballot(lm == wm);
    int first = __ffsll(ball) - 1;
    if (lane == first){
      if      (w0 == wm) w0 = NEG;
      else if (w1 == wm) w1 = NEG;
      else if (w2 == wm) w2 = NEG;
      else               w3 = NEG;
    }
    thr = wm;
  }
  float s = 0.f;
  #pragma unroll
  for (int j = 0; j < 4; j++) s += (v[j] >= thr) ? v[j] : 0.f;
  #pragma unroll
  for (int off = 32; off; off >>= 1) s += __shfl_xor(s, off, 64);
  const float d = s * (1.0f / NB);
  f32x4 o;
  #pragma unroll
  for (int j = 0; j < 4; j++) o[j] = (v[j] >= thr) ? v[j] / d : 0.f;
  *(f32x4*)&part[(size_t)row * NB + lane * 4] = o;
}

// ---------------- K3: gated main GEMM, bf16 MFMA 16x16x32 -------------------
// 128b x 128w tile (one q), 4 waves 64x64. Changes vs 133us version:
// XOR-swizzled linear LDS (no pad; conflict-free frag reads), T14 split
// staging (loads for s+1 issued after barrier), XCD-aware block decode
// (q-mates of a b-tile co-XCD -> A-panel L2 reuse). LDS 41KB -> 3 blocks/CU.
__global__ __launch_bounds__(256) void main_v2(
    const unsigned short* __restrict__ xb,
    const unsigned short* __restrict__ wt,
    const float* __restrict__ g,
    const float* __restrict__ bias,
    float* __restrict__ out)
{
  __shared__ unsigned short XA[128][64];   // gated bf16, swizzled
  __shared__ unsigned short WB[128][64];   // W^T bf16, swizzled
  __shared__ float gl[128 * 17];           // gates [row][p]

  // XCD-aware decode: co-XCD (same f%8) blocks share a b-group of 8 tiles
  const int f  = blockIdx.x;
  const int q  = f >> 6;                        // 0..15
  const int b0 = ((f & 7) * 8 + ((f >> 3) & 7)) * 128;
  const int t    = threadIdx.x;
  const int lane = t & 63;
  const int wid  = t >> 6;
  const int wr   = (wid >> 1) * 64;
  const int wc   = (wid & 1) * 64;
  const int l15  = lane & 15;
  const int l4   = lane >> 4;

  for (int e = t; e < 128 * 16; e += 256){
    const int r = e >> 4, p = e & 15;
    gl[r * 17 + p] = g[(size_t)(b0 + r) * NB + p * 16 + q];
  }

  f32x4 acc[4][4];
  #pragma unroll
  for (int m = 0; m < 4; m++)
    #pragma unroll
    for (int n = 0; n < 4; n++) acc[m][n] = (f32x4)0.0f;

  const int row_s = t >> 1;         // 0..127
  const int half  = t & 1;
  const int kk    = half * 32;

  // hoisted swizzled read offsets (u16 units)
  int aoff[2][4], boff[2][4];
  #pragma unroll
  for (int ksi = 0; ksi < 2; ksi++){
    const int chunk = ksi * 4 + l4;
    #pragma unroll
    for (int m = 0; m < 4; m++){
      const int row = wr + m * 16 + l15;
      aoff[ksi][m] = row * 64 + ((chunk ^ (row & 7)) << 3);
    }
    #pragma unroll
    for (int n = 0; n < 4; n++){
      const int row = wc + n * 16 + l15;
      boff[ksi][n] = row * 64 + ((chunk ^ (row & 7)) << 3);
    }
  }

  u16x8 ax[4], bx[4];
  auto LOAD = [&](int kb){
    const unsigned short* asrc = &xb[(size_t)(b0 + row_s) * DIN + kb + kk];
    const unsigned short* bsrc = &wt[(size_t)(q * 128 + row_s) * DIN + kb + kk];
    #pragma unroll
    for (int j = 0; j < 4; j++){ ax[j] = ((const u16x8*)asrc)[j]; bx[j] = ((const u16x8*)bsrc)[j]; }
  };
  auto WRITE = [&](int p){
    const float gate = gl[row_s * 17 + p];
    const int sw = row_s & 7;
    #pragma unroll
    for (int j = 0; j < 4; j++){
      u16x8 o;
      #pragma unroll
      for (int i = 0; i < 8; i++) o[i] = f2bf_c(bf2f(ax[j][i]) * gate);
      const int c8 = ((half * 4 + j) ^ sw) << 3;
      *(u16x8*)&XA[row_s][c8] = o;
      *(u16x8*)&WB[row_s][c8] = bx[j];
    }
  };

  const unsigned short* A0 = &XA[0][0];
  const unsigned short* B0 = &WB[0][0];

  LOAD(0);
  #pragma unroll 1
  for (int kp = 0; kp < 32; kp++){
    __syncthreads();                  // prev compute done; gl visible (kp=0)
    WRITE(kp >> 1);
    __syncthreads();
    if (kp < 31) LOAD((kp + 1) * 64);
    #pragma unroll
    for (int ksi = 0; ksi < 2; ksi++){
      bf16x8 a[4], b[4];
      #pragma unroll
      for (int m = 0; m < 4; m++) a[m] = *(const bf16x8*)&A0[aoff[ksi][m]];
      #pragma unroll
      for (int n = 0; n < 4; n++) b[n] = *(const bf16x8*)&B0[boff[ksi][n]];
      #pragma unroll
      for (int m = 0; m < 4; m++)
        #pragma unroll
        for (int n = 0; n < 4; n++)
          acc[m][n] = __builtin_amdgcn_mfma_f32_16x16x32_bf16(a[m], b[n], acc[m][n], 0, 0, 0);
    }
  }

  #pragma unroll
  for (int n = 0; n < 4; n++){
    const int col = q * 128 + wc + n * 16 + l15;
    const float bv = bias[col];
    #pragma unroll
    for (int m = 0; m < 4; m++){
      #pragma unroll
      for (int r = 0; r < 4; r++){
        const int row = b0 + wr + m * 16 + l4 * 4 + r;
        out[(size_t)row * DOUT + col] = acc[m][n][r] + bv;
      }
    }
  }
}

// ---------------- launch -----------------------------------------------------
extern "C" void kernel_launch(void* const* d_in, const int* in_sizes, int n_in,
                              void* d_out, int out_size, void* d_ws, size_t ws_size,
                              hipStream_t stream)
{
  const float* x    = (const float*)d_in[0];
  const float* w    = (const float*)d_in[1];
  const float* bias = (const float*)d_in[2];
  const float* gw   = (const float*)d_in[3];
  const float* gb   = (const float*)d_in[4];
  float* out = (float*)d_out;

  // ws layout (56 MiB, proven budget):
  //   [0,16M)  part: 2 f32 splits (split 0 becomes final gates)
  //   [16,48M) xb: bf16(x), emitted by gate_v2, consumed by main_v2
  //   [48,56M) phase A: ghiT@48M, gloT@49M, flags@50M (dead after refine)
  //            phase B: wtb (8 MiB, written by conv_wt AFTER refine)
  char* wsb = (char*)d_ws;
  float*          part = (float*)wsb;
  unsigned short* xbb  = (unsigned short*)(wsb + (size_t)16 * 1024 * 1024);
  unsigned short* ghiT = (unsigned short*)(wsb + (size_t)48 * 1024 * 1024);
  unsigned short* gloT = (unsigned short*)(wsb + (size_t)49 * 1024 * 1024);
  int*            flg  = (int*)           (wsb + (size_t)50 * 1024 * 1024);
  unsigned short* wtb  = (unsigned short*)(wsb + (size_t)48 * 1024 * 1024);

  conv_gwt <<<dim3(DIN / 64, NB / 64), 256, 0, stream>>>(gw, ghiT, gloT);
  gate_v2  <<<dim3(BATCH / 64, 2, 2), 256, 0, stream>>>(x, ghiT, gloT, part, xbb);
  topk     <<<BATCH / 4, 256, 0, stream>>>(part, gb, flg);
  refine   <<<BATCH / 4, 256, 0, stream>>>(x, gw, gb, flg, part);
  conv_wt  <<<dim3(DIN / 64, DOUT / 64), 256, 0, stream>>>(w, wtb);
  main_v2  <<<1024, 256, 0, stream>>>(xbb, wtb, part, bias, out);
}